// Round 3
// baseline (234.005 us; speedup 1.0000x reference)
//
#include <hip/hip_runtime.h>

#define SEQ 2048
#define BSZ 2
#define NH 16
#define DKD 64
#define DM 1024
#define NROW (SEQ*BSZ)   // 4096
#define KDIM 1024

typedef __attribute__((ext_vector_type(8))) short bf16x8;
typedef __attribute__((ext_vector_type(4))) float floatx4;

__device__ __forceinline__ unsigned short f2b(float f) {
  unsigned int u = __builtin_bit_cast(unsigned int, f);
  u += 0x7fffu + ((u >> 16) & 1u);
  return (unsigned short)(u >> 16);
}

__device__ __forceinline__ void async_copy16(void* lds, const void* g) {
  __builtin_amdgcn_global_load_lds(
      (__attribute__((address_space(1))) void*)(void*)g,
      (__attribute__((address_space(3))) void*)lds, 16, 0, 0);
}

__device__ __forceinline__ floatx4 mfma16(bf16x8 a, bf16x8 b, floatx4 c) {
  return __builtin_amdgcn_mfma_f32_16x16x32_bf16(a, b, c, 0, 0, 0);
}

// ---------------- fp32 -> bf16 conversion of x and W(q,k,v) ----------------
// Destination is inside d_out (legal inter-dispatch scratch; attn overwrites
// all of d_out at the end). Keeps d_ws usage at 24 MB total.
__global__ __launch_bounds__(256) void cvt_kernel(
    const float* __restrict__ x, const float* __restrict__ Wq,
    const float* __restrict__ Wk, const float* __restrict__ Wv,
    ushort* __restrict__ xbf, ushort* __restrict__ wbf) {
  size_t tid = (size_t)blockIdx.x * 256 + threadIdx.x;
  size_t i4 = tid * 4;
  const float* src;
  const size_t NX = (size_t)NROW * KDIM;  // 4194304
  ushort* dst;
  size_t off;
  if (i4 < NX) {
    src = x; off = i4; dst = xbf + i4;
  } else {
    size_t wix = i4 - NX;                 // 0 .. 3*1048576
    int proj = (int)(wix >> 20);
    src = proj == 0 ? Wq : (proj == 1 ? Wk : Wv);
    off = wix & 1048575u;
    dst = wbf + wix;
  }
  float4 v = *(const float4*)(src + off);
  ushort4 o;
  o.x = f2b(v.x); o.y = f2b(v.y); o.z = f2b(v.z); o.w = f2b(v.w);
  *(ushort4*)dst = o;
}

// ---------------- QKV projection GEMM: C[4096][3072] = Xbf * Wbf^T ----------
// Q -> Qs [b][h][s][dk] pre-scaled by 0.125; K -> Ks [b][h][s][dk];
// V -> Vt [b][h][dk][s] (directly transposed scatter store).
__global__ __launch_bounds__(256, 2) void gemm_qkv(
    const ushort* __restrict__ xbf, const ushort* __restrict__ wbf,
    const float* __restrict__ bq, const float* __restrict__ bk,
    const float* __restrict__ bvv,
    ushort* __restrict__ Qs, ushort* __restrict__ Ks, ushort* __restrict__ Vt) {
  __shared__ ushort Al[128 * 32];
  __shared__ ushort Bl[128 * 32];
  const int t = threadIdx.x;
  const int w = t >> 6, l = t & 63;
  const int wr = w >> 1, wc = w & 1;
  const int lane15 = l & 15, quad = l >> 4;
  const int rb = blockIdx.x, cb = blockIdx.y;
  const ushort* Ag = xbf + (size_t)rb * 128 * KDIM;
  const ushort* Bg = wbf + (size_t)cb * 128 * KDIM;
  const int rsub = l >> 2, c2 = (l & 3) * 8;

  floatx4 acc[4][4];
  #pragma unroll
  for (int i = 0; i < 4; ++i)
    #pragma unroll
    for (int j = 0; j < 4; ++j) acc[i][j] = (floatx4){0.f, 0.f, 0.f, 0.f};

  for (int kk = 0; kk < KDIM; kk += 32) {
    __syncthreads();
    #pragma unroll
    for (int half = 0; half < 2; ++half) {
      int rloc = w * 32 + half * 16;
      async_copy16(&Al[rloc * 32], Ag + (size_t)(rloc + rsub) * KDIM + kk + c2);
      async_copy16(&Bl[rloc * 32], Bg + (size_t)(rloc + rsub) * KDIM + kk + c2);
    }
    __syncthreads();
    bf16x8 af[4], bfr[4];
    #pragma unroll
    for (int mt = 0; mt < 4; ++mt)
      af[mt] = *(const bf16x8*)&Al[(wr * 64 + mt * 16 + lane15) * 32 + quad * 8];
    #pragma unroll
    for (int nt = 0; nt < 4; ++nt)
      bfr[nt] = *(const bf16x8*)&Bl[(wc * 64 + nt * 16 + lane15) * 32 + quad * 8];
    #pragma unroll
    for (int mt = 0; mt < 4; ++mt)
      #pragma unroll
      for (int nt = 0; nt < 4; ++nt)
        acc[mt][nt] = mfma16(af[mt], bfr[nt], acc[mt][nt]);
  }

  int proj = (cb * 128) >> 10;                 // uniform per block
  const float* bias = proj == 0 ? bq : (proj == 1 ? bk : bvv);
  float scale = proj == 0 ? 0.125f : 1.0f;

  if (proj < 2) {
    ushort* dst = proj == 0 ? Qs : Ks;
    #pragma unroll
    for (int nt = 0; nt < 4; ++nt) {
      int mcol = cb * 128 + wc * 64 + nt * 16 + lane15;
      int cip = mcol & 1023;
      int h = cip >> 6, dk = cip & 63;
      float bias_v = bias[cip];
      #pragma unroll
      for (int mt = 0; mt < 4; ++mt) {
        #pragma unroll
        for (int r = 0; r < 4; ++r) {
          int n = rb * 128 + wr * 64 + mt * 16 + quad * 4 + r;
          int s = n >> 1, b = n & 1;
          float val = (acc[mt][nt][r] + bias_v) * scale;
          dst[((size_t)(b * NH + h) * SEQ + s) * DKD + dk] = f2b(val);
        }
      }
    }
  } else {
    // V: store transposed [b][h][dk][s]
    #pragma unroll
    for (int nt = 0; nt < 4; ++nt) {
      int mcol = cb * 128 + wc * 64 + nt * 16 + lane15;
      int cip = mcol & 1023;
      int h = cip >> 6, dk = cip & 63;
      float bias_v = bias[cip];
      #pragma unroll
      for (int mt = 0; mt < 4; ++mt) {
        #pragma unroll
        for (int r = 0; r < 4; ++r) {
          int n = rb * 128 + wr * 64 + mt * 16 + quad * 4 + r;
          int s = n >> 1, b = n & 1;
          float val = acc[mt][nt][r] + bias_v;
          Vt[((size_t)(b * NH + h) * DKD + dk) * SEQ + s] = f2b(val);
        }
      }
    }
  }
}

// ---------------- fused causal attention with softmax-one -------------------
// grid: (32 q-tiles, 32 bh). block: 256 threads = 4 waves, 16 q-rows each.
__global__ __launch_bounds__(256, 2) void attn_kernel(
    const ushort* __restrict__ Qs, const ushort* __restrict__ Ks,
    const ushort* __restrict__ Vt, float* __restrict__ out) {
  __shared__ ushort Kl[64 * 72];
  __shared__ ushort Vl[64 * 72];
  __shared__ ushort Pl[4][16 * 72];
  const int t = threadIdx.x;
  const int w = t >> 6, l = t & 63;
  const int lane15 = l & 15, quad = l >> 4;
  const int qt = blockIdx.x, bh = blockIdx.y;
  const int b = bh >> 4, h = bh & 15;
  const int qbase = qt * 64;
  const int qrow = qbase + w * 16 + lane15;

  const ushort* Qg = Qs + ((size_t)bh * SEQ + qrow) * DKD;
  bf16x8 qf0 = *(const bf16x8*)(Qg + quad * 8);
  bf16x8 qf1 = *(const bf16x8*)(Qg + 32 + quad * 8);
  const ushort* Kg = Ks + (size_t)bh * SEQ * DKD;
  const ushort* Vg = Vt + (size_t)bh * DKD * SEQ;

  floatx4 o[4];
  #pragma unroll
  for (int i = 0; i < 4; ++i) o[i] = (floatx4){0.f, 0.f, 0.f, 0.f};
  float m_r[4] = {-1e30f, -1e30f, -1e30f, -1e30f};
  float l_r[4] = {0.f, 0.f, 0.f, 0.f};

  for (int kt = 0; kt <= qt; ++kt) {
    __syncthreads();
    #pragma unroll
    for (int c = 0; c < 2; ++c) {
      int idx = t + c * 256;
      int row = idx >> 3, col8 = (idx & 7) * 8;
      *(uint4*)&Kl[row * 72 + col8] =
          *(const uint4*)(Kg + (size_t)(kt * 64 + row) * DKD + col8);
      *(uint4*)&Vl[row * 72 + col8] =
          *(const uint4*)(Vg + (size_t)row * SEQ + kt * 64 + col8);
    }
    __syncthreads();

    floatx4 sf[4];
    #pragma unroll
    for (int nt = 0; nt < 4; ++nt) {
      floatx4 a = (floatx4){0.f, 0.f, 0.f, 0.f};
      bf16x8 k0 = *(const bf16x8*)&Kl[(nt * 16 + lane15) * 72 + quad * 8];
      bf16x8 k1 = *(const bf16x8*)&Kl[(nt * 16 + lane15) * 72 + 32 + quad * 8];
      a = mfma16(qf0, k0, a);
      a = mfma16(qf1, k1, a);
      sf[nt] = a;
    }

    if (kt == qt) {  // diagonal tile: causal mask
      #pragma unroll
      for (int nt = 0; nt < 4; ++nt) {
        int j = kt * 64 + nt * 16 + lane15;
        #pragma unroll
        for (int r = 0; r < 4; ++r) {
          int i = qbase + w * 16 + quad * 4 + r;
          if (j > i) sf[nt][r] = -1e30f;
        }
      }
    }

    float rmax[4];
    #pragma unroll
    for (int r = 0; r < 4; ++r) {
      float v = fmaxf(fmaxf(sf[0][r], sf[1][r]), fmaxf(sf[2][r], sf[3][r]));
      v = fmaxf(v, __shfl_xor(v, 1, 64));
      v = fmaxf(v, __shfl_xor(v, 2, 64));
      v = fmaxf(v, __shfl_xor(v, 4, 64));
      v = fmaxf(v, __shfl_xor(v, 8, 64));
      rmax[r] = v;
    }
    float alpha[4];
    #pragma unroll
    for (int r = 0; r < 4; ++r) {
      float mn = fmaxf(m_r[r], rmax[r]);
      alpha[r] = __expf(m_r[r] - mn);
      m_r[r] = mn;
    }
    float rsum[4] = {0.f, 0.f, 0.f, 0.f};
    #pragma unroll
    for (int nt = 0; nt < 4; ++nt)
      #pragma unroll
      for (int r = 0; r < 4; ++r) {
        float p = __expf(sf[nt][r] - m_r[r]);
        sf[nt][r] = p;
        rsum[r] += p;
      }
    #pragma unroll
    for (int r = 0; r < 4; ++r) {
      float v = rsum[r];
      v += __shfl_xor(v, 1, 64);
      v += __shfl_xor(v, 2, 64);
      v += __shfl_xor(v, 4, 64);
      v += __shfl_xor(v, 8, 64);
      l_r[r] = l_r[r] * alpha[r] + v;
    }
    #pragma unroll
    for (int ntd = 0; ntd < 4; ++ntd)
      #pragma unroll
      for (int r = 0; r < 4; ++r) o[ntd][r] *= alpha[r];

    // P (C-layout) -> LDS -> A-layout fragments (per-wave buffer, wave-ordered DS)
    ushort* Pw = &Pl[w][0];
    #pragma unroll
    for (int nt = 0; nt < 4; ++nt)
      #pragma unroll
      for (int r = 0; r < 4; ++r)
        Pw[(quad * 4 + r) * 72 + nt * 16 + lane15] = f2b(sf[nt][r]);
    asm volatile("s_waitcnt lgkmcnt(0)" ::: "memory");
    bf16x8 pa0 = *(const bf16x8*)&Pw[lane15 * 72 + quad * 8];
    bf16x8 pa1 = *(const bf16x8*)&Pw[lane15 * 72 + 32 + quad * 8];

    #pragma unroll
    for (int ntd = 0; ntd < 4; ++ntd) {
      bf16x8 v0 = *(const bf16x8*)&Vl[(ntd * 16 + lane15) * 72 + quad * 8];
      bf16x8 v1 = *(const bf16x8*)&Vl[(ntd * 16 + lane15) * 72 + 32 + quad * 8];
      o[ntd] = mfma16(pa0, v0, o[ntd]);
      o[ntd] = mfma16(pa1, v1, o[ntd]);
    }
  }

  #pragma unroll
  for (int ntd = 0; ntd < 4; ++ntd) {
    int d = h * DKD + ntd * 16 + lane15;
    #pragma unroll
    for (int r = 0; r < 4; ++r) {
      int i = qbase + w * 16 + quad * 4 + r;
      out[((size_t)i * BSZ + b) * DM + d] = o[ntd][r] / (1.0f + l_r[r]);
    }
  }
}

extern "C" void kernel_launch(void* const* d_in, const int* in_sizes, int n_in,
                              void* d_out, int out_size, void* d_ws, size_t ws_size,
                              hipStream_t stream) {
  (void)in_sizes; (void)n_in; (void)out_size; (void)ws_size;
  const float* x  = (const float*)d_in[0];
  const float* Wq = (const float*)d_in[1];
  const float* bq = (const float*)d_in[2];
  const float* Wk = (const float*)d_in[3];
  const float* bk = (const float*)d_in[4];
  const float* Wv = (const float*)d_in[5];
  const float* bv = (const float*)d_in[6];
  float* out = (float*)d_out;

  // cvt staging lives inside d_out (16 MB): xbf 8 MB + wbf 6 MB.
  // attn fully overwrites d_out at the end.
  ushort* xbf = (ushort*)d_out;                       // [0, 8 MB)
  ushort* wbf = (ushort*)((char*)d_out + 8388608);    // [8 MB, 14.67 MB)

  // d_ws usage: 24 MB total (was 46 MB -> overran ws_size and corrupted
  // the harness's adjacent allocations; this is the round-2 fix).
  char* ws = (char*)d_ws;
  ushort* Qs = (ushort*)(ws);               // [0, 8 MB)
  ushort* Ks = (ushort*)(ws + 8388608);     // [8 MB, 16 MB)
  ushort* Vt = (ushort*)(ws + 16777216);    // [16 MB, 24 MB)

  cvt_kernel<<<dim3(7168), dim3(256), 0, stream>>>(x, Wq, Wk, Wv, xbf, wbf);
  gemm_qkv<<<dim3(32, 24), dim3(256), 0, stream>>>(xbf, wbf, bq, bk, bv, Qs, Ks, Vt);
  attn_kernel<<<dim3(32, 32), dim3(256), 0, stream>>>(Qs, Ks, Vt, out);
}

// Round 4
// 178.708 us; speedup vs baseline: 1.3094x; 1.3094x over previous
//
#include <hip/hip_runtime.h>

#define SEQ 2048
#define BSZ 2
#define NH 16
#define DKD 64
#define DM 1024
#define NROW (SEQ*BSZ)   // 4096
#define KDIM 1024

typedef __attribute__((ext_vector_type(8))) short bf16x8;
typedef __attribute__((ext_vector_type(4))) float floatx4;

__device__ __forceinline__ unsigned short f2b(float f) {
  unsigned int u = __builtin_bit_cast(unsigned int, f);
  u += 0x7fffu + ((u >> 16) & 1u);
  return (unsigned short)(u >> 16);
}

__device__ __forceinline__ void async_copy16(void* lds, const void* g) {
  __builtin_amdgcn_global_load_lds(
      (__attribute__((address_space(1))) void*)(void*)g,
      (__attribute__((address_space(3))) void*)lds, 16, 0, 0);
}

__device__ __forceinline__ floatx4 mfma16(bf16x8 a, bf16x8 b, floatx4 c) {
  return __builtin_amdgcn_mfma_f32_16x16x32_bf16(a, b, c, 0, 0, 0);
}

// ---------------- fp32 -> bf16 conversion of x and W(q,k,v) ----------------
// Destination is inside d_out (legal inter-dispatch scratch; attn overwrites
// all of d_out at the end). Keeps d_ws usage at 24 MB total.
__global__ __launch_bounds__(256) void cvt_kernel(
    const float* __restrict__ x, const float* __restrict__ Wq,
    const float* __restrict__ Wk, const float* __restrict__ Wv,
    ushort* __restrict__ xbf, ushort* __restrict__ wbf) {
  size_t tid = (size_t)blockIdx.x * 256 + threadIdx.x;
  size_t i4 = tid * 4;
  const float* src;
  const size_t NX = (size_t)NROW * KDIM;  // 4194304
  ushort* dst;
  size_t off;
  if (i4 < NX) {
    src = x; off = i4; dst = xbf + i4;
  } else {
    size_t wix = i4 - NX;                 // 0 .. 3*1048576
    int proj = (int)(wix >> 20);
    src = proj == 0 ? Wq : (proj == 1 ? Wk : Wv);
    off = wix & 1048575u;
    dst = wbf + wix;
  }
  float4 v = *(const float4*)(src + off);
  ushort4 o;
  o.x = f2b(v.x); o.y = f2b(v.y); o.z = f2b(v.z); o.w = f2b(v.w);
  *(ushort4*)dst = o;
}

// ---------------- QKV projection GEMM: C[4096][3072] = Xbf * Wbf^T ----------
// Q -> Qs [b][h][s][dk] pre-scaled by 0.125*log2(e) (exp2-domain attention);
// K -> Ks [b][h][s][dk]; V -> Vt [b][h][dk][s] (transposed scatter store).
__global__ __launch_bounds__(256, 2) void gemm_qkv(
    const ushort* __restrict__ xbf, const ushort* __restrict__ wbf,
    const float* __restrict__ bq, const float* __restrict__ bk,
    const float* __restrict__ bvv,
    ushort* __restrict__ Qs, ushort* __restrict__ Ks, ushort* __restrict__ Vt) {
  __shared__ ushort Al[128 * 32];
  __shared__ ushort Bl[128 * 32];
  const int t = threadIdx.x;
  const int w = t >> 6, l = t & 63;
  const int wr = w >> 1, wc = w & 1;
  const int lane15 = l & 15, quad = l >> 4;
  const int rb = blockIdx.x, cb = blockIdx.y;
  const ushort* Ag = xbf + (size_t)rb * 128 * KDIM;
  const ushort* Bg = wbf + (size_t)cb * 128 * KDIM;
  const int rsub = l >> 2, c2 = (l & 3) * 8;

  floatx4 acc[4][4];
  #pragma unroll
  for (int i = 0; i < 4; ++i)
    #pragma unroll
    for (int j = 0; j < 4; ++j) acc[i][j] = (floatx4){0.f, 0.f, 0.f, 0.f};

  for (int kk = 0; kk < KDIM; kk += 32) {
    __syncthreads();
    #pragma unroll
    for (int half = 0; half < 2; ++half) {
      int rloc = w * 32 + half * 16;
      async_copy16(&Al[rloc * 32], Ag + (size_t)(rloc + rsub) * KDIM + kk + c2);
      async_copy16(&Bl[rloc * 32], Bg + (size_t)(rloc + rsub) * KDIM + kk + c2);
    }
    __syncthreads();
    bf16x8 af[4], bfr[4];
    #pragma unroll
    for (int mt = 0; mt < 4; ++mt)
      af[mt] = *(const bf16x8*)&Al[(wr * 64 + mt * 16 + lane15) * 32 + quad * 8];
    #pragma unroll
    for (int nt = 0; nt < 4; ++nt)
      bfr[nt] = *(const bf16x8*)&Bl[(wc * 64 + nt * 16 + lane15) * 32 + quad * 8];
    #pragma unroll
    for (int mt = 0; mt < 4; ++mt)
      #pragma unroll
      for (int nt = 0; nt < 4; ++nt)
        acc[mt][nt] = mfma16(af[mt], bfr[nt], acc[mt][nt]);
  }

  int proj = (cb * 128) >> 10;                 // uniform per block
  const float* bias = proj == 0 ? bq : (proj == 1 ? bk : bvv);
  // Q scale folds in log2(e) so attention exp() is a bare v_exp_f32 (2^x).
  float scale = proj == 0 ? 0.125f * 1.44269504088896f : 1.0f;

  if (proj < 2) {
    ushort* dst = proj == 0 ? Qs : Ks;
    #pragma unroll
    for (int nt = 0; nt < 4; ++nt) {
      int mcol = cb * 128 + wc * 64 + nt * 16 + lane15;
      int cip = mcol & 1023;
      int h = cip >> 6, dk = cip & 63;
      float bias_v = bias[cip];
      #pragma unroll
      for (int mt = 0; mt < 4; ++mt) {
        #pragma unroll
        for (int r = 0; r < 4; ++r) {
          int n = rb * 128 + wr * 64 + mt * 16 + quad * 4 + r;
          int s = n >> 1, b = n & 1;
          float val = (acc[mt][nt][r] + bias_v) * scale;
          dst[((size_t)(b * NH + h) * SEQ + s) * DKD + dk] = f2b(val);
        }
      }
    }
  } else {
    // V: store transposed [b][h][dk][s]
    #pragma unroll
    for (int nt = 0; nt < 4; ++nt) {
      int mcol = cb * 128 + wc * 64 + nt * 16 + lane15;
      int cip = mcol & 1023;
      int h = cip >> 6, dk = cip & 63;
      float bias_v = bias[cip];
      #pragma unroll
      for (int mt = 0; mt < 4; ++mt) {
        #pragma unroll
        for (int r = 0; r < 4; ++r) {
          int n = rb * 128 + wr * 64 + mt * 16 + quad * 4 + r;
          int s = n >> 1, b = n & 1;
          float val = acc[mt][nt][r] + bias_v;
          Vt[((size_t)(b * NH + h) * DKD + dk) * SEQ + s] = f2b(val);
        }
      }
    }
  }
}

// ---------------- fused causal attention with softmax-one -------------------
// grid: (32 q-tiles scrambled, 32 bh). block: 256 thr = 4 waves, 16 q-rows/wave.
// Software-pipelined K/V staging; exp2-domain softmax; row-sum via MFMA.
__global__ __launch_bounds__(256, 4) void attn_kernel(
    const ushort* __restrict__ Qs, const ushort* __restrict__ Ks,
    const ushort* __restrict__ Vt, float* __restrict__ out) {
  __shared__ ushort Kl[64 * 72];
  __shared__ ushort Vl[64 * 72];
  __shared__ ushort Pl[4][16 * 72];
  const int t = threadIdx.x;
  const int w = t >> 6, l = t & 63;
  const int lane15 = l & 15, quad = l >> 4;
  // scramble qt across block ids so co-resident blocks have mixed work
  const int qt = (blockIdx.x * 13 + blockIdx.y * 7) & 31;
  const int bh = blockIdx.y;
  const int b = bh >> 4, h = bh & 15;
  const int qbase = qt * 64;
  const int qrow = qbase + w * 16 + lane15;

  const ushort* Qg = Qs + ((size_t)bh * SEQ + qrow) * DKD;
  bf16x8 qf0 = *(const bf16x8*)(Qg + quad * 8);
  bf16x8 qf1 = *(const bf16x8*)(Qg + 32 + quad * 8);
  const ushort* Kg = Ks + (size_t)bh * SEQ * DKD;
  const ushort* Vg = Vt + (size_t)bh * DKD * SEQ;

  const int srow = t >> 3;        // 0..31
  const int scol = (t & 7) * 8;

  floatx4 o[4];
  #pragma unroll
  for (int i = 0; i < 4; ++i) o[i] = (floatx4){0.f, 0.f, 0.f, 0.f};
  floatx4 lacc = (floatx4){0.f, 0.f, 0.f, 0.f};
  float m_r[4] = {-1e30f, -1e30f, -1e30f, -1e30f};

  bf16x8 ones;
  #pragma unroll
  for (int j = 0; j < 8; ++j) ones[j] = (short)0x3F80;  // bf16 1.0

  // prefetch tile kt=0 into registers
  uint4 kr0 = *(const uint4*)(Kg + (size_t)srow * DKD + scol);
  uint4 kr1 = *(const uint4*)(Kg + (size_t)(srow + 32) * DKD + scol);
  uint4 vr0 = *(const uint4*)(Vg + (size_t)srow * SEQ + scol);
  uint4 vr1 = *(const uint4*)(Vg + (size_t)(srow + 32) * SEQ + scol);

  for (int kt = 0; kt <= qt; ++kt) {
    __syncthreads();
    *(uint4*)&Kl[srow * 72 + scol] = kr0;
    *(uint4*)&Kl[(srow + 32) * 72 + scol] = kr1;
    *(uint4*)&Vl[srow * 72 + scol] = vr0;
    *(uint4*)&Vl[(srow + 32) * 72 + scol] = vr1;
    __syncthreads();

    if (kt < qt) {  // prefetch next tile; overlaps with compute below
      const ushort* Kn = Kg + (size_t)(kt + 1) * 64 * DKD;
      const ushort* Vn = Vg + (kt + 1) * 64;
      kr0 = *(const uint4*)(Kn + (size_t)srow * DKD + scol);
      kr1 = *(const uint4*)(Kn + (size_t)(srow + 32) * DKD + scol);
      vr0 = *(const uint4*)(Vn + (size_t)srow * SEQ + scol);
      vr1 = *(const uint4*)(Vn + (size_t)(srow + 32) * SEQ + scol);
    }

    floatx4 sf[4];
    #pragma unroll
    for (int nt = 0; nt < 4; ++nt) {
      floatx4 a = (floatx4){0.f, 0.f, 0.f, 0.f};
      bf16x8 k0 = *(const bf16x8*)&Kl[(nt * 16 + lane15) * 72 + quad * 8];
      bf16x8 k1 = *(const bf16x8*)&Kl[(nt * 16 + lane15) * 72 + 32 + quad * 8];
      a = mfma16(qf0, k0, a);
      a = mfma16(qf1, k1, a);
      sf[nt] = a;
    }

    if (kt == qt) {  // diagonal tile: causal mask
      #pragma unroll
      for (int nt = 0; nt < 4; ++nt) {
        int j = kt * 64 + nt * 16 + lane15;
        #pragma unroll
        for (int r = 0; r < 4; ++r) {
          int i = qbase + w * 16 + quad * 4 + r;
          if (j > i) sf[nt][r] = -1e30f;
        }
      }
    }

    float alpha[4];
    #pragma unroll
    for (int r = 0; r < 4; ++r) {
      float v = fmaxf(fmaxf(sf[0][r], sf[1][r]), fmaxf(sf[2][r], sf[3][r]));
      v = fmaxf(v, __shfl_xor(v, 1, 64));
      v = fmaxf(v, __shfl_xor(v, 2, 64));
      v = fmaxf(v, __shfl_xor(v, 4, 64));
      v = fmaxf(v, __shfl_xor(v, 8, 64));
      float mn = fmaxf(m_r[r], v);
      alpha[r] = __builtin_amdgcn_exp2f(m_r[r] - mn);
      m_r[r] = mn;
    }
    // p = exp2(s' - m'); write bf16 (truncation) into per-wave P buffer
    ushort* Pw = &Pl[w][0];
    #pragma unroll
    for (int nt = 0; nt < 4; ++nt)
      #pragma unroll
      for (int r = 0; r < 4; ++r) {
        float p = __builtin_amdgcn_exp2f(sf[nt][r] - m_r[r]);
        Pw[(quad * 4 + r) * 72 + nt * 16 + lane15] =
            (ushort)(__builtin_bit_cast(unsigned int, p) >> 16);
      }
    // rescale accumulators while P writes are in flight
    #pragma unroll
    for (int ntd = 0; ntd < 4; ++ntd)
      #pragma unroll
      for (int r = 0; r < 4; ++r) o[ntd][r] *= alpha[r];
    #pragma unroll
    for (int r = 0; r < 4; ++r) lacc[r] *= alpha[r];

    asm volatile("s_waitcnt lgkmcnt(0)" ::: "memory");
    bf16x8 pa0 = *(const bf16x8*)&Pw[lane15 * 72 + quad * 8];
    bf16x8 pa1 = *(const bf16x8*)&Pw[lane15 * 72 + 32 + quad * 8];

    // row-sum of P via MFMA against all-ones B (every output col = row sum)
    lacc = mfma16(pa0, ones, lacc);
    lacc = mfma16(pa1, ones, lacc);

    #pragma unroll
    for (int ntd = 0; ntd < 4; ++ntd) {
      bf16x8 v0 = *(const bf16x8*)&Vl[(ntd * 16 + lane15) * 72 + quad * 8];
      bf16x8 v1 = *(const bf16x8*)&Vl[(ntd * 16 + lane15) * 72 + 32 + quad * 8];
      o[ntd] = mfma16(pa0, v0, o[ntd]);
      o[ntd] = mfma16(pa1, v1, o[ntd]);
    }
  }

  float inv[4];
  #pragma unroll
  for (int r = 0; r < 4; ++r) inv[r] = 1.0f / (1.0f + lacc[r]);
  #pragma unroll
  for (int ntd = 0; ntd < 4; ++ntd) {
    int d = h * DKD + ntd * 16 + lane15;
    #pragma unroll
    for (int r = 0; r < 4; ++r) {
      int i = qbase + w * 16 + quad * 4 + r;
      out[((size_t)i * BSZ + b) * DM + d] = o[ntd][r] * inv[r];
    }
  }
}

extern "C" void kernel_launch(void* const* d_in, const int* in_sizes, int n_in,
                              void* d_out, int out_size, void* d_ws, size_t ws_size,
                              hipStream_t stream) {
  (void)in_sizes; (void)n_in; (void)out_size; (void)ws_size;
  const float* x  = (const float*)d_in[0];
  const float* Wq = (const float*)d_in[1];
  const float* bq = (const float*)d_in[2];
  const float* Wk = (const float*)d_in[3];
  const float* bk = (const float*)d_in[4];
  const float* Wv = (const float*)d_in[5];
  const float* bv = (const float*)d_in[6];
  float* out = (float*)d_out;

  // cvt staging lives inside d_out (16 MB): xbf 8 MB + wbf 6 MB.
  ushort* xbf = (ushort*)d_out;                       // [0, 8 MB)
  ushort* wbf = (ushort*)((char*)d_out + 8388608);    // [8 MB, 14.67 MB)

  // d_ws usage: 24 MB total.
  char* ws = (char*)d_ws;
  ushort* Qs = (ushort*)(ws);               // [0, 8 MB)
  ushort* Ks = (ushort*)(ws + 8388608);     // [8 MB, 16 MB)
  ushort* Vt = (ushort*)(ws + 16777216);    // [16 MB, 24 MB)

  cvt_kernel<<<dim3(7168), dim3(256), 0, stream>>>(x, Wq, Wk, Wv, xbf, wbf);
  gemm_qkv<<<dim3(32, 24), dim3(256), 0, stream>>>(xbf, wbf, bq, bk, bv, Qs, Ks, Vt);
  attn_kernel<<<dim3(32, 32), dim3(256), 0, stream>>>(Qs, Ks, Vt, out);
}

// Round 5
// 174.781 us; speedup vs baseline: 1.3388x; 1.0225x over previous
//
#include <hip/hip_runtime.h>

#define SEQ 2048
#define BSZ 2
#define NH 16
#define DKD 64
#define DM 1024
#define NROW (SEQ*BSZ)   // 4096
#define KDIM 1024

typedef __attribute__((ext_vector_type(8))) short bf16x8;
typedef __attribute__((ext_vector_type(4))) float floatx4;

__device__ __forceinline__ unsigned short f2b(float f) {
  unsigned int u = __builtin_bit_cast(unsigned int, f);
  u += 0x7fffu + ((u >> 16) & 1u);
  return (unsigned short)(u >> 16);
}

__device__ __forceinline__ void async_copy16(void* lds, const void* g) {
  __builtin_amdgcn_global_load_lds(
      (__attribute__((address_space(1))) void*)(void*)g,
      (__attribute__((address_space(3))) void*)lds, 16, 0, 0);
}

__device__ __forceinline__ floatx4 mfma16(bf16x8 a, bf16x8 b, floatx4 c) {
  return __builtin_amdgcn_mfma_f32_16x16x32_bf16(a, b, c, 0, 0, 0);
}

// ---------------- fp32 -> bf16 conversion of x and W(q,k,v) ----------------
__global__ __launch_bounds__(256) void cvt_kernel(
    const float* __restrict__ x, const float* __restrict__ Wq,
    const float* __restrict__ Wk, const float* __restrict__ Wv,
    ushort* __restrict__ xbf, ushort* __restrict__ wbf) {
  size_t tid = (size_t)blockIdx.x * 256 + threadIdx.x;
  size_t i4 = tid * 4;
  const float* src;
  const size_t NX = (size_t)NROW * KDIM;  // 4194304
  ushort* dst;
  size_t off;
  if (i4 < NX) {
    src = x; off = i4; dst = xbf + i4;
  } else {
    size_t wix = i4 - NX;                 // 0 .. 3*1048576
    int proj = (int)(wix >> 20);
    src = proj == 0 ? Wq : (proj == 1 ? Wk : Wv);
    off = wix & 1048575u;
    dst = wbf + wix;
  }
  float4 v = *(const float4*)(src + off);
  ushort4 o;
  o.x = f2b(v.x); o.y = f2b(v.y); o.z = f2b(v.z); o.w = f2b(v.w);
  *(ushort4*)dst = o;
}

// ---------------- QKV projection GEMM: C[4096][3072] = Xbf * Wbf^T ----------
// Q -> Qs [b][h][s][dk] pre-scaled by 0.125*log2(e); K -> Ks [b][h][s][dk];
// V -> Vt [b][h][dk][s]. Epilogue stages the C-tile in LDS and writes out
// with 16B contiguous stores (was: 64 scattered 2B stores per thread).
__global__ __launch_bounds__(256, 2) void gemm_qkv(
    const ushort* __restrict__ xbf, const ushort* __restrict__ wbf,
    const float* __restrict__ bq, const float* __restrict__ bk,
    const float* __restrict__ bvv,
    ushort* __restrict__ Qs, ushort* __restrict__ Ks, ushort* __restrict__ Vt) {
  __shared__ ushort Al[128 * 32];
  __shared__ ushort Bl[128 * 32];
  __shared__ ushort Cl[128 * 136];   // epilogue staging, pad 136 (16B rows)
  const int t = threadIdx.x;
  const int w = t >> 6, l = t & 63;
  const int wr = w >> 1, wc = w & 1;
  const int lane15 = l & 15, quad = l >> 4;
  const int rb = blockIdx.x, cb = blockIdx.y;
  const ushort* Ag = xbf + (size_t)rb * 128 * KDIM;
  const ushort* Bg = wbf + (size_t)cb * 128 * KDIM;
  const int rsub = l >> 2, c2 = (l & 3) * 8;

  floatx4 acc[4][4];
  #pragma unroll
  for (int i = 0; i < 4; ++i)
    #pragma unroll
    for (int j = 0; j < 4; ++j) acc[i][j] = (floatx4){0.f, 0.f, 0.f, 0.f};

  for (int kk = 0; kk < KDIM; kk += 32) {
    __syncthreads();
    #pragma unroll
    for (int half = 0; half < 2; ++half) {
      int rloc = w * 32 + half * 16;
      async_copy16(&Al[rloc * 32], Ag + (size_t)(rloc + rsub) * KDIM + kk + c2);
      async_copy16(&Bl[rloc * 32], Bg + (size_t)(rloc + rsub) * KDIM + kk + c2);
    }
    __syncthreads();
    bf16x8 af[4], bfr[4];
    #pragma unroll
    for (int mt = 0; mt < 4; ++mt)
      af[mt] = *(const bf16x8*)&Al[(wr * 64 + mt * 16 + lane15) * 32 + quad * 8];
    #pragma unroll
    for (int nt = 0; nt < 4; ++nt)
      bfr[nt] = *(const bf16x8*)&Bl[(wc * 64 + nt * 16 + lane15) * 32 + quad * 8];
    #pragma unroll
    for (int mt = 0; mt < 4; ++mt)
      #pragma unroll
      for (int nt = 0; nt < 4; ++nt)
        acc[mt][nt] = mfma16(af[mt], bfr[nt], acc[mt][nt]);
  }

  int proj = (cb * 128) >> 10;                 // uniform per block
  const float* bias = proj == 0 ? bq : (proj == 1 ? bk : bvv);
  float scale = proj == 0 ? 0.125f * 1.44269504088896f : 1.0f;
  bool isV = (proj == 2);

  // stage C tile into LDS (per-lane scalar writes, conflict-tolerable)
  #pragma unroll
  for (int nt = 0; nt < 4; ++nt) {
    int c = wc * 64 + nt * 16 + lane15;
    int cip = (cb * 128 + c) & 1023;
    float bias_v = bias[cip];
    #pragma unroll
    for (int mt = 0; mt < 4; ++mt) {
      #pragma unroll
      for (int r = 0; r < 4; ++r) {
        int n = wr * 64 + mt * 16 + quad * 4 + r;
        float val = (acc[mt][nt][r] + bias_v) * scale;
        if (!isV) Cl[n * 136 + c] = f2b(val);
        else      Cl[c * 136 + (n & 1) * 64 + (n >> 1)] = f2b(val);
      }
    }
  }
  __syncthreads();

  if (!isV) {
    ushort* dst = proj == 0 ? Qs : Ks;
    // thread t: b = t>>7, s_local = t&63, chunk(head-half) = (t>>6)&1
    int b = t >> 7;
    int sl = t & 63;
    int chunk = (t >> 6) & 1;
    int n = (sl << 1) | b;
    int cip = (cb * 128 + chunk * 64) & 1023;
    int h = cip >> 6;
    int s = rb * 64 + sl;
    ushort* g = dst + (((size_t)(b * NH + h) * SEQ + s) * DKD);
    const uint4* s4 = (const uint4*)&Cl[n * 136 + chunk * 64];
    #pragma unroll
    for (int j = 0; j < 8; ++j) *(uint4*)(g + j * 8) = s4[j];
  } else {
    // thread t: c = t>>1 (tile col), b = t&1; 64 s-values contiguous
    int c = t >> 1, b = t & 1;
    int cip = (cb * 128 + c) & 1023;
    int h = cip >> 6, dk = c & 63;
    ushort* g = Vt + ((size_t)(b * NH + h) * DKD + dk) * SEQ + rb * 64;
    const uint4* s4 = (const uint4*)&Cl[c * 136 + b * 64];
    #pragma unroll
    for (int j = 0; j < 8; ++j) *(uint4*)(g + j * 8) = s4[j];
  }
}

// ---------------- fused causal attention with softmax-one -------------------
// Paired q-tiles: block (qa, bh) processes q-tile qa then q-tile 31-qa as one
// flat 33-iteration loop -> every block identical work (zero tail).
// Double-buffered K/V LDS, one barrier per iteration, register prefetch.
__global__ __launch_bounds__(256, 2) void attn_kernel(
    const ushort* __restrict__ Qs, const ushort* __restrict__ Ks,
    const ushort* __restrict__ Vt, float* __restrict__ out) {
  __shared__ ushort Kl[2][64 * 72];
  __shared__ ushort Vl[2][64 * 72];
  __shared__ ushort Pl[4][16 * 72];
  const int t = threadIdx.x;
  const int w = t >> 6, l = t & 63;
  const int lane15 = l & 15, quad = l >> 4;
  const int qa = blockIdx.x;            // 0..15
  const int bh = blockIdx.y;
  const int b = bh >> 4, h = bh & 15;
  const int qtB = 31 - qa;

  const ushort* Kg = Ks + (size_t)bh * SEQ * DKD;
  const ushort* Vg = Vt + (size_t)bh * DKD * SEQ;
  const int srow = t >> 3;              // 0..31
  const int scol = (t & 7) * 8;

  int qt = qa;
  int qbase = qt * 64;
  const ushort* Qg = Qs + ((size_t)bh * SEQ + qbase + w * 16 + lane15) * DKD;
  bf16x8 qf0 = *(const bf16x8*)(Qg + quad * 8);
  bf16x8 qf1 = *(const bf16x8*)(Qg + 32 + quad * 8);

  floatx4 o[4];
  #pragma unroll
  for (int i = 0; i < 4; ++i) o[i] = (floatx4){0.f, 0.f, 0.f, 0.f};
  floatx4 lacc = (floatx4){0.f, 0.f, 0.f, 0.f};
  float m_r[4] = {-1e30f, -1e30f, -1e30f, -1e30f};

  bf16x8 ones;
  #pragma unroll
  for (int j = 0; j < 8; ++j) ones[j] = (short)0x3F80;  // bf16 1.0

  // kt for flat iteration j (j<=qa: phase A, else phase B)
  #define KT_OF(j) ((j) <= qa ? (j) : (j) - qa - 1)

  // preload tile 0 -> regs -> buf 0; prefetch tile for it=1
  uint4 kr0, kr1, vr0, vr1;
  {
    int kt0 = 0;
    kr0 = *(const uint4*)(Kg + (size_t)(kt0 * 64 + srow) * DKD + scol);
    kr1 = *(const uint4*)(Kg + (size_t)(kt0 * 64 + srow + 32) * DKD + scol);
    vr0 = *(const uint4*)(Vg + (size_t)srow * SEQ + kt0 * 64 + scol);
    vr1 = *(const uint4*)(Vg + (size_t)(srow + 32) * SEQ + kt0 * 64 + scol);
    *(uint4*)&Kl[0][srow * 72 + scol] = kr0;
    *(uint4*)&Kl[0][(srow + 32) * 72 + scol] = kr1;
    *(uint4*)&Vl[0][srow * 72 + scol] = vr0;
    *(uint4*)&Vl[0][(srow + 32) * 72 + scol] = vr1;
    int kt1 = KT_OF(1);
    kr0 = *(const uint4*)(Kg + (size_t)(kt1 * 64 + srow) * DKD + scol);
    kr1 = *(const uint4*)(Kg + (size_t)(kt1 * 64 + srow + 32) * DKD + scol);
    vr0 = *(const uint4*)(Vg + (size_t)srow * SEQ + kt1 * 64 + scol);
    vr1 = *(const uint4*)(Vg + (size_t)(srow + 32) * SEQ + kt1 * 64 + scol);
  }

  for (int it = 0; it <= 32; ++it) {
    const int cur = it & 1;
    const int kt = KT_OF(it);
    __syncthreads();

    floatx4 sf[4];
    #pragma unroll
    for (int nt = 0; nt < 4; ++nt) {
      floatx4 a = (floatx4){0.f, 0.f, 0.f, 0.f};
      bf16x8 k0 = *(const bf16x8*)&Kl[cur][(nt * 16 + lane15) * 72 + quad * 8];
      bf16x8 k1 = *(const bf16x8*)&Kl[cur][(nt * 16 + lane15) * 72 + 32 + quad * 8];
      a = mfma16(qf0, k0, a);
      a = mfma16(qf1, k1, a);
      sf[nt] = a;
    }

    if (kt == qt) {  // diagonal tile: causal mask
      #pragma unroll
      for (int nt = 0; nt < 4; ++nt) {
        int j = kt * 64 + nt * 16 + lane15;
        #pragma unroll
        for (int r = 0; r < 4; ++r) {
          int i = qbase + w * 16 + quad * 4 + r;
          if (j > i) sf[nt][r] = -1e30f;
        }
      }
    }

    float alpha[4];
    #pragma unroll
    for (int r = 0; r < 4; ++r) {
      float v = fmaxf(fmaxf(sf[0][r], sf[1][r]), fmaxf(sf[2][r], sf[3][r]));
      v = fmaxf(v, __shfl_xor(v, 1, 64));
      v = fmaxf(v, __shfl_xor(v, 2, 64));
      v = fmaxf(v, __shfl_xor(v, 4, 64));
      v = fmaxf(v, __shfl_xor(v, 8, 64));
      float mn = fmaxf(m_r[r], v);
      alpha[r] = __builtin_amdgcn_exp2f(m_r[r] - mn);
      m_r[r] = mn;
    }
    ushort* Pw = &Pl[w][0];
    #pragma unroll
    for (int nt = 0; nt < 4; ++nt)
      #pragma unroll
      for (int r = 0; r < 4; ++r) {
        float p = __builtin_amdgcn_exp2f(sf[nt][r] - m_r[r]);
        Pw[(quad * 4 + r) * 72 + nt * 16 + lane15] =
            (ushort)(__builtin_bit_cast(unsigned int, p) >> 16);
      }
    #pragma unroll
    for (int ntd = 0; ntd < 4; ++ntd)
      #pragma unroll
      for (int r = 0; r < 4; ++r) o[ntd][r] *= alpha[r];
    #pragma unroll
    for (int r = 0; r < 4; ++r) lacc[r] *= alpha[r];

    asm volatile("s_waitcnt lgkmcnt(0)" ::: "memory");
    bf16x8 pa0 = *(const bf16x8*)&Pw[lane15 * 72 + quad * 8];
    bf16x8 pa1 = *(const bf16x8*)&Pw[lane15 * 72 + 32 + quad * 8];

    lacc = mfma16(pa0, ones, lacc);
    lacc = mfma16(pa1, ones, lacc);

    #pragma unroll
    for (int ntd = 0; ntd < 4; ++ntd) {
      bf16x8 v0 = *(const bf16x8*)&Vl[cur][(ntd * 16 + lane15) * 72 + quad * 8];
      bf16x8 v1 = *(const bf16x8*)&Vl[cur][(ntd * 16 + lane15) * 72 + 32 + quad * 8];
      o[ntd] = mfma16(pa0, v0, o[ntd]);
      o[ntd] = mfma16(pa1, v1, o[ntd]);
    }

    // flush finished q-tile (end of phase A or end of loop)
    if (it == qa || it == 32) {
      float inv[4];
      #pragma unroll
      for (int r = 0; r < 4; ++r) inv[r] = 1.0f / (1.0f + lacc[r]);
      #pragma unroll
      for (int ntd = 0; ntd < 4; ++ntd) {
        int d = h * DKD + ntd * 16 + lane15;
        #pragma unroll
        for (int r = 0; r < 4; ++r) {
          int i = qbase + w * 16 + quad * 4 + r;
          out[((size_t)i * BSZ + b) * DM + d] = o[ntd][r] * inv[r];
        }
      }
      if (it == qa) {  // switch to phase B
        #pragma unroll
        for (int i = 0; i < 4; ++i) o[i] = (floatx4){0.f, 0.f, 0.f, 0.f};
        lacc = (floatx4){0.f, 0.f, 0.f, 0.f};
        #pragma unroll
        for (int r = 0; r < 4; ++r) m_r[r] = -1e30f;
        qt = qtB;
        qbase = qt * 64;
        const ushort* Qg2 = Qs + ((size_t)bh * SEQ + qbase + w * 16 + lane15) * DKD;
        qf0 = *(const bf16x8*)(Qg2 + quad * 8);
        qf1 = *(const bf16x8*)(Qg2 + 32 + quad * 8);
      }
    }

    // stage tile it+1 (regs -> idle buffer); prefetch tile it+2
    if (it < 32) {
      int nxt = cur ^ 1;
      *(uint4*)&Kl[nxt][srow * 72 + scol] = kr0;
      *(uint4*)&Kl[nxt][(srow + 32) * 72 + scol] = kr1;
      *(uint4*)&Vl[nxt][srow * 72 + scol] = vr0;
      *(uint4*)&Vl[nxt][(srow + 32) * 72 + scol] = vr1;
      if (it + 2 <= 32) {
        int kt2 = KT_OF(it + 2);
        kr0 = *(const uint4*)(Kg + (size_t)(kt2 * 64 + srow) * DKD + scol);
        kr1 = *(const uint4*)(Kg + (size_t)(kt2 * 64 + srow + 32) * DKD + scol);
        vr0 = *(const uint4*)(Vg + (size_t)srow * SEQ + kt2 * 64 + scol);
        vr1 = *(const uint4*)(Vg + (size_t)(srow + 32) * SEQ + kt2 * 64 + scol);
      }
    }
  }
  #undef KT_OF
}

extern "C" void kernel_launch(void* const* d_in, const int* in_sizes, int n_in,
                              void* d_out, int out_size, void* d_ws, size_t ws_size,
                              hipStream_t stream) {
  (void)in_sizes; (void)n_in; (void)out_size; (void)ws_size;
  const float* x  = (const float*)d_in[0];
  const float* Wq = (const float*)d_in[1];
  const float* bq = (const float*)d_in[2];
  const float* Wk = (const float*)d_in[3];
  const float* bk = (const float*)d_in[4];
  const float* Wv = (const float*)d_in[5];
  const float* bv = (const float*)d_in[6];
  float* out = (float*)d_out;

  // cvt staging lives inside d_out (16 MB): xbf 8 MB + wbf 6 MB.
  ushort* xbf = (ushort*)d_out;                       // [0, 8 MB)
  ushort* wbf = (ushort*)((char*)d_out + 8388608);    // [8 MB, 14.67 MB)

  // d_ws usage: 24 MB total.
  char* ws = (char*)d_ws;
  ushort* Qs = (ushort*)(ws);               // [0, 8 MB)
  ushort* Ks = (ushort*)(ws + 8388608);     // [8 MB, 16 MB)
  ushort* Vt = (ushort*)(ws + 16777216);    // [16 MB, 24 MB)

  cvt_kernel<<<dim3(7168), dim3(256), 0, stream>>>(x, Wq, Wk, Wv, xbf, wbf);
  gemm_qkv<<<dim3(32, 24), dim3(256), 0, stream>>>(xbf, wbf, bq, bk, bv, Qs, Ks, Vt);
  attn_kernel<<<dim3(16, 32), dim3(256), 0, stream>>>(Qs, Ks, Vt, out);
}